// Round 2
// baseline (96.539 us; speedup 1.0000x reference)
//
#include <hip/hip_runtime.h>

// Problem: B=16, S=2048, D=64, fp32.
// out[b] = V[b] @ (K[b]^T @ Q[b])   -- avoids the SxS intermediate.
//
// R7: kill LDS traffic instead of adding waves (R6's occupancy bump was null;
// both kernels were LDS-pipe-bound at ~2 B/FMA = ~1 MB/block through a
// ~85 B/cyc pipe). Operands here are broadcast-heavy (4-16 distinct addrs
// per wave), which L1 serves natively:
//   A: NO LDS. ak = one 64B line/wave, bq = 4 lines/wave, straight from
//      global (L2-warm, L1-reused 16x). No staging, no barriers, no tail.
//   B: only the 16 KB M-reduce stays in LDS; V rows read direct from global
//      (each V line reused 16x across tx-threads via L1). VsT transpose
//      scatter and second barrier deleted.
// Same math, same P layout, same output addressing as R5/R6.

typedef float vf4 __attribute__((ext_vector_type(4)));

#define BATCH 16
#define SEQ   2048
#define DIM   64
#define SCHUNK 128                 // seq rows per block, kernel A
#define NCHUNK (SEQ / SCHUNK)      // 16
#define ROWS2  128                 // V rows per block, kernel B

// ---------------- Kernel A: P[bx] = K_chunk^T @ Q_chunk ----------------------
// 256 threads, 4x4 register tile, zero LDS. Thread (ty,tx) owns
// M[ty*4..+3][tx*4..+3]. Loads served by L1 (ak: 4 distinct 16B/wave in one
// 64B line; bq: 16 distinct in 4 lines). unroll 8 -> 16 outstanding loads
// covers ~200cyc L2 latency at 1 wave/SIMD.
__global__ __launch_bounds__(256) void ktq_part_kernel(
        const float* __restrict__ K, const float* __restrict__ Q,
        float* __restrict__ P) {
    const int b     = blockIdx.y;
    const int chunk = blockIdx.x;
    const int t     = threadIdx.x;
    const int tx    = t & 15;   // d  (Q) cols tx*4 .. +3
    const int ty    = t >> 4;   // d' (K) rows ty*4 .. +3

    const float* Kb = K + ((size_t)b * SEQ + (size_t)chunk * SCHUNK) * DIM + ty * 4;
    const float* Qb = Q + ((size_t)b * SEQ + (size_t)chunk * SCHUNK) * DIM + tx * 4;

    float acc[4][4] = {};
#pragma unroll 8
    for (int s = 0; s < SCHUNK; ++s) {
        vf4 ak = *(const vf4*)&Kb[s * DIM];
        vf4 bq = *(const vf4*)&Qb[s * DIM];
#pragma unroll
        for (int i = 0; i < 4; ++i)
#pragma unroll
            for (int j = 0; j < 4; ++j) acc[i][j] += ak[i] * bq[j];
    }

    float* Pb = P + ((size_t)b * NCHUNK + chunk) * DIM * DIM;
#pragma unroll
    for (int i = 0; i < 4; ++i) {
        vf4 r = {acc[i][0], acc[i][1], acc[i][2], acc[i][3]};
        *(vf4*)&Pb[(ty * 4 + i) * DIM + tx * 4] = r;
    }
}

// ---------------- Kernel B: O rows = V rows @ sum_c P[b][c] ------------------
// 512 threads, 128 rows/block, 4x4 register tile. M (16 KB) reduced into LDS;
// V read direct from global (no transpose staging). Per dp-chunk of 4:
// 4 b128 LDS reads (M rows, 2-way bank alias = free) + 4 vf4 global V reads.
__global__ __launch_bounds__(512) void vm_red_kernel(
        const float* __restrict__ V, const float* __restrict__ P,
        float* __restrict__ O) {
    __shared__ __attribute__((aligned(16))) float Ml[DIM * DIM];   // 16 KB, M[d'][d]
    const int b  = blockIdx.y;
    const int rb = blockIdx.x;
    const int t  = threadIdx.x;

    // Reduce the 16 partials of this batch: 1024 vf4 / 512 thr -> 2 each.
    const float* Pb = P + (size_t)b * NCHUNK * DIM * DIM;
#pragma unroll
    for (int i = 0; i < 2; ++i) {
        int idx = i * 512 + t;
        vf4 sum = ((const vf4*)Pb)[idx];
#pragma unroll
        for (int c = 1; c < NCHUNK; ++c)
            sum += ((const vf4*)(Pb + (size_t)c * DIM * DIM))[idx];
        ((vf4*)Ml)[idx] = sum;
    }
    __syncthreads();

    const int tx = t & 15;   // output cols d = tx*4 .. +3
    const int ty = t >> 4;   // output rows v = ty*4 .. +3 (0..31 -> 128 rows)
    const float* Vb = V + ((size_t)b * SEQ + (size_t)rb * ROWS2 + ty * 4) * DIM;

    float acc[4][4] = {};
#pragma unroll 4
    for (int dpc = 0; dpc < DIM / 4; ++dpc) {
        vf4 m0 = *(const vf4*)&Ml[(dpc * 4 + 0) * DIM + tx * 4];
        vf4 m1 = *(const vf4*)&Ml[(dpc * 4 + 1) * DIM + tx * 4];
        vf4 m2 = *(const vf4*)&Ml[(dpc * 4 + 2) * DIM + tx * 4];
        vf4 m3 = *(const vf4*)&Ml[(dpc * 4 + 3) * DIM + tx * 4];
#pragma unroll
        for (int i = 0; i < 4; ++i) {
            vf4 v = *(const vf4*)&Vb[i * DIM + dpc * 4];
#pragma unroll
            for (int j = 0; j < 4; ++j) {
                acc[i][j] += v[0] * m0[j] + v[1] * m1[j]
                           + v[2] * m2[j] + v[3] * m3[j];
            }
        }
    }

    float* Ob = O + ((size_t)b * SEQ + (size_t)rb * ROWS2) * DIM;
#pragma unroll
    for (int i = 0; i < 4; ++i) {
        vf4 o = {acc[i][0], acc[i][1], acc[i][2], acc[i][3]};
        __builtin_nontemporal_store(o, (vf4*)&Ob[(ty * 4 + i) * DIM + tx * 4]);
    }
}

extern "C" void kernel_launch(void* const* d_in, const int* in_sizes, int n_in,
                              void* d_out, int out_size, void* d_ws, size_t ws_size,
                              hipStream_t stream) {
    const float* Q = (const float*)d_in[0];
    const float* K = (const float*)d_in[1];
    const float* V = (const float*)d_in[2];
    float* O = (float*)d_out;
    float* P = (float*)d_ws;   // BATCH*NCHUNK*64*64 floats = 4 MB of partials

    dim3 gridA(NCHUNK, BATCH);        // 256 blocks, 256 thr
    ktq_part_kernel<<<gridA, 256, 0, stream>>>(K, Q, P);

    dim3 gridB(SEQ / ROWS2, BATCH);   // 256 blocks, 512 thr
    vm_red_kernel<<<gridB, 512, 0, stream>>>(V, P, O);
}

// Round 3
// 88.649 us; speedup vs baseline: 1.0890x; 1.0890x over previous
//
#include <hip/hip_runtime.h>

// Problem: B=16, S=2048, D=64, fp32.
// out[b] = V[b] @ (K[b]^T @ Q[b])   -- avoids the SxS intermediate.
//
// R8: revert R7 (direct-global regressed +10us: 128KB block working set
// thrashes 32KB L1). Keep R5 two-dispatch LDS structure but halve the
// LDS-pipe work with bigger register tiles:
//   A: 8x8 tiles. 1 wave's 64 lanes cover the whole 64x64 M-chunk; the 4
//      waves split the 128 s-rows 4-ways (32 each), LDS-reduce tail.
//      Per s-step/wave: 4 ds_read_b128 -> 64 FMA (was 2 -> 16). Staging is
//      per-wave-private -> no initial barrier.
//   B: 4x8 tiles, 512 thr, dp split 2x32, V staged via in-register 4x4
//      transpose (4 b128 writes per 16 floats, was 16 b32 scatter stores).
// Both main loops now VALU-bound (~4096 cyc/SIMD) instead of LDS-bound.

typedef float vf4 __attribute__((ext_vector_type(4)));

#define BATCH 16
#define SEQ   2048
#define DIM   64
#define SCHUNK 128                 // seq rows per block, kernel A
#define NCHUNK (SEQ / SCHUNK)      // 16
#define SW     (SCHUNK / 4)        // 32 s-rows per wave, kernel A
#define ROWS2  128                 // V rows per block, kernel B
#define TPADR  132                 // transposed-V row stride (floats): %32=4 -> 8 bank-group spread, 16B-aligned
#define RSTRA  68                  // A-tail lane stride (floats): %32=4 -> optimal spread, 272B b128-aligned
#define RSTRB  36                  // B-tail thread stride (floats): %32=4 -> optimal spread, 144B b128-aligned

// ---------------- Kernel A: P[bx] = K_chunk^T @ Q_chunk ----------------------
// 256 thr = 4 waves. Wave w owns s-rows [w*32, w*32+32); lane l: ty=l>>3 ->
// K cols ty*8..+7, tx=l&7 -> Q cols tx*8..+7; acc[8][8]. Cross-wave reduce
// through (reused) staging LDS, wave 0 stores the 64x64 chunk.
__global__ __launch_bounds__(256) void ktq_part_kernel(
        const float* __restrict__ K, const float* __restrict__ Q,
        float* __restrict__ P) {
    __shared__ __attribute__((aligned(16))) float Sm[2 * SCHUNK * DIM];  // 64 KB
    float* Ks = Sm;
    float* Qs = Sm + SCHUNK * DIM;
    const int b = blockIdx.y, chunk = blockIdx.x, t = threadIdx.x;
    const int w = t >> 6, l = t & 63;

    // Per-wave staging: wave w stages only its own 32 rows of K and Q.
    const size_t rowbase = ((size_t)b * SEQ + (size_t)chunk * SCHUNK + (size_t)w * SW) * DIM;
    const vf4* Kg = (const vf4*)(K + rowbase);
    const vf4* Qg = (const vf4*)(Q + rowbase);
    vf4* KsW = (vf4*)(Ks + w * SW * DIM);
    vf4* QsW = (vf4*)(Qs + w * SW * DIM);
#pragma unroll
    for (int j = 0; j < 8; ++j) {
        KsW[j * 64 + l] = Kg[j * 64 + l];
        QsW[j * 64 + l] = Qg[j * 64 + l];
    }
    // No block barrier: each wave consumes only the rows it staged
    // (intra-wave ds_write->ds_read ordering handled by compiler lgkmcnt).

    const int tx = l & 7, ty = l >> 3;
    const float* KsR = Ks + w * SW * DIM + ty * 8;
    const float* QsR = Qs + w * SW * DIM + tx * 8;
    float acc[8][8] = {};
#pragma unroll 2
    for (int s = 0; s < SW; ++s) {
        vf4 a0 = *(const vf4*)&KsR[s * DIM];
        vf4 a1 = *(const vf4*)&KsR[s * DIM + 4];
        vf4 b0 = *(const vf4*)&QsR[s * DIM];
        vf4 b1 = *(const vf4*)&QsR[s * DIM + 4];
        float a[8]  = {a0[0], a0[1], a0[2], a0[3], a1[0], a1[1], a1[2], a1[3]};
        float bb[8] = {b0[0], b0[1], b0[2], b0[3], b1[0], b1[1], b1[2], b1[3]};
#pragma unroll
        for (int i = 0; i < 8; ++i)
#pragma unroll
            for (int j = 0; j < 8; ++j) acc[i][j] += a[i] * bb[j];
    }

    // Cross-wave reduce: staging regions are dead after the barrier; waves
    // 1..3 park 64x64 partials (3 * 64 * 68 floats = 52 KB <= 64 KB).
    __syncthreads();
    if (w != 0) {
        float* Rs = Sm + (size_t)(w - 1) * 64 * RSTRA + l * RSTRA;
#pragma unroll
        for (int i = 0; i < 8; ++i) {
            vf4 r0 = {acc[i][0], acc[i][1], acc[i][2], acc[i][3]};
            vf4 r1 = {acc[i][4], acc[i][5], acc[i][6], acc[i][7]};
            *(vf4*)&Rs[i * 8]     = r0;
            *(vf4*)&Rs[i * 8 + 4] = r1;
        }
    }
    __syncthreads();
    if (w == 0) {
        float* Pb = P + ((size_t)b * NCHUNK + chunk) * DIM * DIM
                  + (size_t)(ty * 8) * DIM + tx * 8;
#pragma unroll
        for (int i = 0; i < 8; ++i) {
#pragma unroll
            for (int jh = 0; jh < 2; ++jh) {
                vf4 sum = {acc[i][jh * 4 + 0], acc[i][jh * 4 + 1],
                           acc[i][jh * 4 + 2], acc[i][jh * 4 + 3]};
#pragma unroll
                for (int p = 0; p < 3; ++p)
                    sum += *(const vf4*)&Sm[(size_t)p * 64 * RSTRA + l * RSTRA
                                            + i * 8 + jh * 4];
                *(vf4*)&Pb[i * DIM + jh * 4] = sum;
            }
        }
    }
}

// ---------------- Kernel B: O rows = V rows @ sum_c P[b][c] ------------------
// 512 thr = 2 dp-groups x 256. Group g covers dp = g*32..+31. Thread sub:
// tx=sub&7 -> cols tx*8..+7, ty=sub>>3 -> rows ty*4..+3; acc[4][8].
__global__ __launch_bounds__(512) void vm_red_kernel(
        const float* __restrict__ V, const float* __restrict__ P,
        float* __restrict__ O) {
    __shared__ __attribute__((aligned(16))) float Sm[DIM * DIM + DIM * TPADR]; // 49 KB
    float* Ml  = Sm;                 // [64][64]  M[d'][d]
    float* VsT = Sm + DIM * DIM;     // [64][TPADR]  VsT[col][row]
    const int b = blockIdx.y, rb = blockIdx.x, t = threadIdx.x;

    // Reduce the 16 partials of this batch: 1024 vf4 / 512 thr -> 2 each.
    const float* Pb = P + (size_t)b * NCHUNK * DIM * DIM;
#pragma unroll
    for (int i = 0; i < 2; ++i) {
        int idx = i * 512 + t;
        vf4 sum = ((const vf4*)Pb)[idx];
#pragma unroll
        for (int c = 1; c < NCHUNK; ++c)
            sum += ((const vf4*)(Pb + (size_t)c * DIM * DIM))[idx];
        ((vf4*)Ml)[idx] = sum;
    }

    // Stage 128 V rows transposed via in-register 4x4 transpose:
    // 512 4x4-blocks, one per thread: 4 vf4 loads + 4 b128 stores.
    const float* Vb = V + ((size_t)b * SEQ + (size_t)rb * ROWS2) * DIM;
    {
        const int r0 = (t >> 4) * 4;     // 0..124
        const int c0 = (t & 15) * 4;     // 0..60
        vf4 tmp[4];
#pragma unroll
        for (int r = 0; r < 4; ++r)
            tmp[r] = *(const vf4*)&Vb[(size_t)(r0 + r) * DIM + c0];
#pragma unroll
        for (int c = 0; c < 4; ++c) {
            vf4 wv = {tmp[0][c], tmp[1][c], tmp[2][c], tmp[3][c]};
            *(vf4*)&VsT[(size_t)(c0 + c) * TPADR + r0] = wv;
        }
    }
    __syncthreads();

    const int g = t >> 8, sub = t & 255;
    const int tx = sub & 7, ty = sub >> 3;   // cols tx*8..+7, rows ty*4..+3
    float acc[4][8] = {};
#pragma unroll 2
    for (int d0 = 0; d0 < 32; ++d0) {
        const int dp = g * 32 + d0;
        vf4 m0 = *(const vf4*)&Ml[dp * DIM + tx * 8];
        vf4 m1 = *(const vf4*)&Ml[dp * DIM + tx * 8 + 4];
        vf4 av = *(const vf4*)&VsT[dp * TPADR + ty * 4];
        float m[8] = {m0[0], m0[1], m0[2], m0[3], m1[0], m1[1], m1[2], m1[3]};
#pragma unroll
        for (int i = 0; i < 4; ++i)
#pragma unroll
            for (int j = 0; j < 8; ++j) acc[i][j] += av[i] * m[j];
    }

    // Cross-group reduce: group 1 parks 256*36 floats = 36 KB in (dead)
    // Ml+VsT region; group 0 sums and stores.
    __syncthreads();
    if (g == 1) {
        float* Rs = Sm + (size_t)sub * RSTRB;
#pragma unroll
        for (int i = 0; i < 4; ++i) {
            vf4 r0 = {acc[i][0], acc[i][1], acc[i][2], acc[i][3]};
            vf4 r1 = {acc[i][4], acc[i][5], acc[i][6], acc[i][7]};
            *(vf4*)&Rs[i * 8]     = r0;
            *(vf4*)&Rs[i * 8 + 4] = r1;
        }
    }
    __syncthreads();
    if (g == 0) {
        const float* Rs = Sm + (size_t)sub * RSTRB;
        float* Ob = O + ((size_t)b * SEQ + (size_t)rb * ROWS2 + (size_t)ty * 4) * DIM
                  + tx * 8;
#pragma unroll
        for (int i = 0; i < 4; ++i) {
#pragma unroll
            for (int jh = 0; jh < 2; ++jh) {
                vf4 s0 = {acc[i][jh * 4 + 0], acc[i][jh * 4 + 1],
                          acc[i][jh * 4 + 2], acc[i][jh * 4 + 3]};
                vf4 s1 = *(const vf4*)&Rs[i * 8 + jh * 4];
                vf4 o = s0 + s1;
                __builtin_nontemporal_store(o, (vf4*)&Ob[i * DIM + jh * 4]);
            }
        }
    }
}

extern "C" void kernel_launch(void* const* d_in, const int* in_sizes, int n_in,
                              void* d_out, int out_size, void* d_ws, size_t ws_size,
                              hipStream_t stream) {
    const float* Q = (const float*)d_in[0];
    const float* K = (const float*)d_in[1];
    const float* V = (const float*)d_in[2];
    float* O = (float*)d_out;
    float* P = (float*)d_ws;   // BATCH*NCHUNK*64*64 floats = 4 MB of partials

    dim3 gridA(NCHUNK, BATCH);        // 256 blocks, 256 thr
    ktq_part_kernel<<<gridA, 256, 0, stream>>>(K, Q, P);

    dim3 gridB(SEQ / ROWS2, BATCH);   // 256 blocks, 512 thr
    vm_red_kernel<<<gridB, 512, 0, stream>>>(V, P, O);
}